// Round 1
// baseline (272.684 us; speedup 1.0000x reference)
//
#include <hip/hip_runtime.h>
#include <hip/hip_bf16.h>
#include <float.h>
#include <limits.h>

#define FEAT       256
#define GAMMA_F    0.1f
#define EPS_F      1e-8f
#define KSEL       64      // BUDGET
#define NB1        64      // stage-1 blocks
#define SLICE      784     // ceil(50000/64) rounded up to x16; 64*784 = 50176 >= 50000
#define M2         (NB1 * KSEL)  // 4096 survivors into stage 2

// ---------------------------------------------------------------------------
// Kernel 1: one 64-lane wave per candidate. Each lane loads float4 (16B) of
// the candidate row and of injected_feat, accumulates dot and squared norms,
// reduces across the wave via shfl_xor, lane 0 writes the edge score.
// ---------------------------------------------------------------------------
__global__ __launch_bounds__(256) void edge_score_kernel(
    const float* __restrict__ infl,
    const float* __restrict__ feats,
    const int*   __restrict__ cand,
    const float* __restrict__ inj,
    float*       __restrict__ scores,   // d_out + KSEL
    int num_cand)
{
    const int gtid = blockIdx.x * blockDim.x + threadIdx.x;
    const int wave = gtid >> 6;
    const int lane = threadIdx.x & 63;
    if (wave >= num_cand) return;

    const int row = cand[wave];
    const float4 f = *reinterpret_cast<const float4*>(
        feats + (size_t)row * FEAT + lane * 4);
    const float4 g = *reinterpret_cast<const float4*>(inj + lane * 4);

    float dot = f.x * g.x + f.y * g.y + f.z * g.z + f.w * g.w;
    float nf  = f.x * f.x + f.y * f.y + f.z * f.z + f.w * f.w;
    float ng  = g.x * g.x + g.y * g.y + g.z * g.z + g.w * g.w;

    #pragma unroll
    for (int off = 32; off > 0; off >>= 1) {
        dot += __shfl_xor(dot, off);
        nf  += __shfl_xor(nf, off);
        ng  += __shfl_xor(ng, off);
    }

    if (lane == 0) {
        const float denom = fmaxf(sqrtf(nf), EPS_F) * fmaxf(sqrtf(ng), EPS_F);
        scores[wave] = infl[wave] - GAMMA_F * (dot / denom);
    }
}

// ---------------------------------------------------------------------------
// Block argmax helpers: reduce (val, global_idx, lds_slot) with jax top_k
// tie-break (equal value -> lower index wins).
// ---------------------------------------------------------------------------
__device__ __forceinline__ void wave_argmax(float& bv, int& bi, int& bs)
{
    #pragma unroll
    for (int off = 32; off > 0; off >>= 1) {
        const float ov = __shfl_xor(bv, off);
        const int   oi = __shfl_xor(bi, off);
        const int   os = __shfl_xor(bs, off);
        if (ov > bv || (ov == bv && oi < bi)) { bv = ov; bi = oi; bs = os; }
    }
}

// ---------------------------------------------------------------------------
// Kernel 2 (stage 1): 64 blocks x 256 threads. Block b stages scores
// [b*SLICE, b*SLICE+SLICE) into LDS, then performs KSEL serial block-argmax
// passes, invalidating each winner, emitting a descending-sorted local top-64.
// ---------------------------------------------------------------------------
__global__ __launch_bounds__(256) void topk_stage1(
    const float* __restrict__ scores,
    float* __restrict__ out_v,
    int*   __restrict__ out_i,
    int num_cand)
{
    __shared__ float sv[SLICE];
    __shared__ int   si[SLICE];
    __shared__ float wv[4];
    __shared__ int   wbi[4];
    __shared__ int   wbs[4];

    const int b    = blockIdx.x;
    const int base = b * SLICE;

    for (int t = threadIdx.x; t < SLICE; t += 256) {
        const int g = base + t;
        sv[t] = (g < num_cand) ? scores[g] : -INFINITY;
        si[t] = (g < num_cand) ? g : INT_MAX;
    }
    __syncthreads();

    for (int k = 0; k < KSEL; ++k) {
        float bv = -INFINITY; int bi = INT_MAX; int bs = 0;
        for (int t = threadIdx.x; t < SLICE; t += 256) {
            const float v = sv[t];
            const int   i = si[t];
            if (v > bv || (v == bv && i < bi)) { bv = v; bi = i; bs = t; }
        }
        wave_argmax(bv, bi, bs);
        const int w = threadIdx.x >> 6;
        if ((threadIdx.x & 63) == 0) { wv[w] = bv; wbi[w] = bi; wbs[w] = bs; }
        __syncthreads();
        if (threadIdx.x == 0) {
            float fv = wv[0]; int fi = wbi[0]; int fs = wbs[0];
            #pragma unroll
            for (int j = 1; j < 4; ++j)
                if (wv[j] > fv || (wv[j] == fv && wbi[j] < fi)) {
                    fv = wv[j]; fi = wbi[j]; fs = wbs[j];
                }
            out_v[b * KSEL + k] = fv;
            out_i[b * KSEL + k] = fi;
            sv[fs] = -INFINITY;
            si[fs] = INT_MAX;
        }
        __syncthreads();
    }
}

// ---------------------------------------------------------------------------
// Kernel 3 (stage 2): single block, 256 threads. Reduce the 4096 stage-1
// survivors to the global top-64; write candidate_indices[pos] as float.
// ---------------------------------------------------------------------------
__global__ __launch_bounds__(256) void topk_stage2(
    const float* __restrict__ in_v,
    const int*   __restrict__ in_i,
    const int*   __restrict__ cand,
    float*       __restrict__ out,   // d_out[0..KSEL)
    int m)
{
    __shared__ float sv[M2];
    __shared__ int   si[M2];
    __shared__ float wv[4];
    __shared__ int   wbi[4];
    __shared__ int   wbs[4];

    for (int t = threadIdx.x; t < M2; t += 256) {
        sv[t] = (t < m) ? in_v[t] : -INFINITY;
        si[t] = (t < m) ? in_i[t] : INT_MAX;
    }
    __syncthreads();

    for (int k = 0; k < KSEL; ++k) {
        float bv = -INFINITY; int bi = INT_MAX; int bs = 0;
        for (int t = threadIdx.x; t < M2; t += 256) {
            const float v = sv[t];
            const int   i = si[t];
            if (v > bv || (v == bv && i < bi)) { bv = v; bi = i; bs = t; }
        }
        wave_argmax(bv, bi, bs);
        const int w = threadIdx.x >> 6;
        if ((threadIdx.x & 63) == 0) { wv[w] = bv; wbi[w] = bi; wbs[w] = bs; }
        __syncthreads();
        if (threadIdx.x == 0) {
            float fv = wv[0]; int fi = wbi[0]; int fs = wbs[0];
            #pragma unroll
            for (int j = 1; j < 4; ++j)
                if (wv[j] > fv || (wv[j] == fv && wbi[j] < fi)) {
                    fv = wv[j]; fi = wbi[j]; fs = wbs[j];
                }
            out[k] = (float)cand[fi];   // selected node index, as f32
            sv[fs] = -INFINITY;
            si[fs] = INT_MAX;
        }
        __syncthreads();
    }
}

extern "C" void kernel_launch(void* const* d_in, const int* in_sizes, int n_in,
                              void* d_out, int out_size, void* d_ws, size_t ws_size,
                              hipStream_t stream) {
    const float* infl  = (const float*)d_in[0];   // [num_cand]
    const float* feats = (const float*)d_in[1];   // [num_nodes, 256]
    const int*   cand  = (const int*)d_in[2];     // [num_cand]
    const float* inj   = (const float*)d_in[3];   // [256]

    const int num_cand = in_sizes[0];

    float* out    = (float*)d_out;          // [0..64): indices-as-f32
    float* scores = (float*)d_out + KSEL;   // [64..64+num_cand): edge scores

    float* ws_v = (float*)d_ws;                       // M2 floats
    int*   ws_i = (int*)((float*)d_ws + M2);          // M2 ints

    // Kernel 1: one wave per candidate, 4 waves per block.
    {
        const int waves_per_block = 4;
        const int blocks = (num_cand + waves_per_block - 1) / waves_per_block;
        edge_score_kernel<<<blocks, 256, 0, stream>>>(
            infl, feats, cand, inj, scores, num_cand);
    }

    // Kernel 2: 64 blocks -> 4096 local-top candidates.
    topk_stage1<<<NB1, 256, 0, stream>>>(scores, ws_v, ws_i, num_cand);

    // Kernel 3: final top-64, sorted descending.
    topk_stage2<<<1, 256, 0, stream>>>(ws_v, ws_i, cand, out, M2);
}

// Round 2
// 49.429 us; speedup vs baseline: 5.5167x; 5.5167x over previous
//
#include <hip/hip_runtime.h>
#include <hip/hip_bf16.h>
#include <float.h>
#include <limits.h>

#define FEAT       256
#define GAMMA_F    0.1f
#define EPS_F      1e-8f
#define KSEL       64        // BUDGET
#define NBUCK      8192      // 13-bit histogram of flipped-float keys
#define CAP        4096      // compaction capacity (expected ~150 used)

// Monotonic float -> uint transform (ascending order preserved).
__device__ __forceinline__ unsigned key_of(float v) {
    unsigned u = __float_as_uint(v);
    return u ^ ((u >> 31) ? 0xFFFFFFFFu : 0x80000000u);
}

// ---------------------------------------------------------------------------
// Kernel 1: one 64-lane wave per candidate. Each lane loads float4 (16B) of
// the candidate row and of injected_feat, accumulates dot and squared norms,
// reduces across the wave via shfl_xor, lane 0 writes the edge score.
// ---------------------------------------------------------------------------
__global__ __launch_bounds__(256) void edge_score_kernel(
    const float* __restrict__ infl,
    const float* __restrict__ feats,
    const int*   __restrict__ cand,
    const float* __restrict__ inj,
    float*       __restrict__ scores,   // d_out + KSEL
    int num_cand)
{
    const int gtid = blockIdx.x * blockDim.x + threadIdx.x;
    const int wave = gtid >> 6;
    const int lane = threadIdx.x & 63;
    if (wave >= num_cand) return;

    const int row = cand[wave];
    const float4 f = *reinterpret_cast<const float4*>(
        feats + (size_t)row * FEAT + lane * 4);
    const float4 g = *reinterpret_cast<const float4*>(inj + lane * 4);

    float dot = f.x * g.x + f.y * g.y + f.z * g.z + f.w * g.w;
    float nf  = f.x * f.x + f.y * f.y + f.z * f.z + f.w * f.w;
    float ng  = g.x * g.x + g.y * g.y + g.z * g.z + g.w * g.w;

    #pragma unroll
    for (int off = 32; off > 0; off >>= 1) {
        dot += __shfl_xor(dot, off);
        nf  += __shfl_xor(nf, off);
        ng  += __shfl_xor(ng, off);
    }

    if (lane == 0) {
        const float denom = fmaxf(sqrtf(nf), EPS_F) * fmaxf(sqrtf(ng), EPS_F);
        scores[wave] = infl[wave] - GAMMA_F * (dot / denom);
    }
}

// ---------------------------------------------------------------------------
// Kernel 2: 13-bit histogram of score keys. LDS pre-aggregation, then merge
// nonzero buckets into the global histogram (max 64 atomics per bucket).
// ---------------------------------------------------------------------------
__global__ __launch_bounds__(256) void hist_kernel(
    const float* __restrict__ scores,
    unsigned*    __restrict__ hist,
    int n)
{
    __shared__ unsigned h[NBUCK];
    for (int i = threadIdx.x; i < NBUCK; i += 256) h[i] = 0;
    __syncthreads();
    for (int i = blockIdx.x * 256 + threadIdx.x; i < n; i += gridDim.x * 256)
        atomicAdd(&h[key_of(scores[i]) >> 19], 1u);
    __syncthreads();
    for (int i = threadIdx.x; i < NBUCK; i += 256)
        if (h[i]) atomicAdd(&hist[i], h[i]);
}

// ---------------------------------------------------------------------------
// Kernel 3: find threshold bucket B = highest bucket such that the count of
// elements in buckets >= B reaches KSEL. Chunked suffix-scan, 1 block.
// ---------------------------------------------------------------------------
__global__ __launch_bounds__(256) void scan_kernel(
    const unsigned* __restrict__ hist,
    unsigned*       __restrict__ meta)   // meta[0] = B
{
    __shared__ unsigned csum[256];
    const int t  = threadIdx.x;
    const int hi = NBUCK - 32 * t;      // exclusive; chunk t = next 32 buckets down
    unsigned s = 0;
    for (int b = hi - 32; b < hi; ++b) s += hist[b];
    csum[t] = s;
    __syncthreads();

    if (t == 0) {
        unsigned cum = 0;
        int tc = 0;
        for (; tc < 256; ++tc) {
            if (cum + csum[tc] >= KSEL) break;
            cum += csum[tc];
        }
        unsigned B = 0;
        if (tc < 256) {
            int b = NBUCK - 32 * tc - 1;
            for (int k = 0; k < 32; ++k, --b) {
                cum += hist[b];
                if (cum >= KSEL) { B = (unsigned)b; break; }
            }
        }
        meta[0] = B;   // fewer than KSEL total -> B=0 (take everything)
    }
}

// ---------------------------------------------------------------------------
// Kernel 4: compact all candidates with bucket >= B into (value, index) lists.
// Order is nondeterministic; the final sort makes the output deterministic.
// ---------------------------------------------------------------------------
__global__ __launch_bounds__(256) void compact_kernel(
    const float*    __restrict__ scores,
    const unsigned* __restrict__ meta,
    unsigned*       __restrict__ cnt,
    float*          __restrict__ out_v,
    int*            __restrict__ out_i,
    int n)
{
    const unsigned B = meta[0];
    for (int i = blockIdx.x * 256 + threadIdx.x; i < n; i += gridDim.x * 256) {
        const float v = scores[i];
        if ((key_of(v) >> 19) >= B) {
            const unsigned p = atomicAdd(cnt, 1u);
            if (p < CAP) { out_v[p] = v; out_i[p] = i; }
        }
    }
}

// ---------------------------------------------------------------------------
// Kernel 5: final exact top-64. Fast path: bitonic sort of 256 slots
// (value desc, index asc). Fallback (m > 256, never expected): serial argmax.
// ---------------------------------------------------------------------------
__device__ __forceinline__ bool comes_first(float va, int ia, float vb, int ib) {
    return (va > vb) || (va == vb && ia < ib);
}

__global__ __launch_bounds__(256) void final_kernel(
    const unsigned* __restrict__ cnt,
    const float*    __restrict__ in_v,
    const int*      __restrict__ in_i,
    const int*      __restrict__ cand,
    float*          __restrict__ out)   // d_out[0..KSEL)
{
    __shared__ float sv[CAP];
    __shared__ int   si[CAP];
    const int t = threadIdx.x;
    const int m = (int)min(*cnt, (unsigned)CAP);

    if (m <= 256) {
        sv[t] = (t < m) ? in_v[t] : -INFINITY;
        si[t] = (t < m) ? in_i[t] : INT_MAX;
        __syncthreads();
        for (int k = 2; k <= 256; k <<= 1) {
            for (int j = k >> 1; j > 0; j >>= 1) {
                const int p = t ^ j;
                if (p > t) {
                    const float va = sv[t], vb = sv[p];
                    const int   ia = si[t], ib = si[p];
                    const bool asc = ((t & k) == 0);
                    const bool doSwap = asc ? comes_first(vb, ib, va, ia)
                                            : comes_first(va, ia, vb, ib);
                    if (doSwap) { sv[t] = vb; si[t] = ib; sv[p] = va; si[p] = ia; }
                }
                __syncthreads();
            }
        }
        if (t < KSEL) out[t] = (float)cand[si[t]];
        return;
    }

    // Fallback: serial argmax over m (<= CAP) elements.
    __shared__ float wv[4];
    __shared__ int   wbi[4], wbs[4];
    for (int i = t; i < CAP; i += 256) {
        sv[i] = (i < m) ? in_v[i] : -INFINITY;
        si[i] = (i < m) ? in_i[i] : INT_MAX;
    }
    __syncthreads();
    for (int k = 0; k < KSEL; ++k) {
        float bv = -INFINITY; int bi = INT_MAX; int bs = 0;
        for (int i = t; i < CAP; i += 256) {
            if (comes_first(sv[i], si[i], bv, bi)) { bv = sv[i]; bi = si[i]; bs = i; }
        }
        #pragma unroll
        for (int off = 32; off > 0; off >>= 1) {
            const float ov = __shfl_xor(bv, off);
            const int   oi = __shfl_xor(bi, off);
            const int   os = __shfl_xor(bs, off);
            if (comes_first(ov, oi, bv, bi)) { bv = ov; bi = oi; bs = os; }
        }
        const int w = t >> 6;
        if ((t & 63) == 0) { wv[w] = bv; wbi[w] = bi; wbs[w] = bs; }
        __syncthreads();
        if (t == 0) {
            float fv = wv[0]; int fi = wbi[0]; int fs = wbs[0];
            #pragma unroll
            for (int j = 1; j < 4; ++j)
                if (comes_first(wv[j], wbi[j], fv, fi)) { fv = wv[j]; fi = wbi[j]; fs = wbs[j]; }
            out[k] = (float)cand[fi];
            sv[fs] = -INFINITY;
            si[fs] = INT_MAX;
        }
        __syncthreads();
    }
}

extern "C" void kernel_launch(void* const* d_in, const int* in_sizes, int n_in,
                              void* d_out, int out_size, void* d_ws, size_t ws_size,
                              hipStream_t stream) {
    const float* infl  = (const float*)d_in[0];   // [num_cand]
    const float* feats = (const float*)d_in[1];   // [num_nodes, 256]
    const int*   cand  = (const int*)d_in[2];     // [num_cand]
    const float* inj   = (const float*)d_in[3];   // [256]

    const int num_cand = in_sizes[0];

    float* out    = (float*)d_out;          // [0..64): indices-as-f32
    float* scores = (float*)d_out + KSEL;   // [64..64+num_cand): edge scores

    unsigned* ws_hist = (unsigned*)d_ws;              // NBUCK
    unsigned* ws_cnt  = ws_hist + NBUCK;              // 1
    unsigned* ws_meta = ws_cnt + 1;                   // 1 (threshold bucket B)
    float*    ws_v    = (float*)(ws_meta + 1);        // CAP
    int*      ws_i    = (int*)(ws_v + CAP);           // CAP

    // Zero histogram + counter (meta is overwritten by scan_kernel).
    hipMemsetAsync(ws_hist, 0, (NBUCK + 2) * sizeof(unsigned), stream);

    // 1. Edge scores: one wave per candidate, 4 waves per block.
    {
        const int blocks = (num_cand + 3) / 4;
        edge_score_kernel<<<blocks, 256, 0, stream>>>(
            infl, feats, cand, inj, scores, num_cand);
    }

    // 2. Histogram of score keys.
    hist_kernel<<<64, 256, 0, stream>>>(scores, ws_hist, num_cand);

    // 3. Threshold bucket.
    scan_kernel<<<1, 256, 0, stream>>>(ws_hist, ws_meta);

    // 4. Compact survivors.
    compact_kernel<<<64, 256, 0, stream>>>(scores, ws_meta, ws_cnt, ws_v, ws_i, num_cand);

    // 5. Exact top-64 via bitonic sort.
    final_kernel<<<1, 256, 0, stream>>>(ws_cnt, ws_v, ws_i, cand, out);
}